// Round 1
// baseline (386.130 us; speedup 1.0000x reference)
//
#include <hip/hip_runtime.h>

typedef __attribute__((ext_vector_type(8))) short bf16x8;
typedef __attribute__((ext_vector_type(4))) float floatx4;
typedef __attribute__((ext_vector_type(4))) unsigned short u16x4;

#define MFMA16(a, b, c) __builtin_amdgcn_mfma_f32_16x16x32_bf16(a, b, c, 0, 0, 0)

__device__ __forceinline__ unsigned short f2bf(float f) {
  unsigned int u = __float_as_uint(f);
  u += 0x7fffu + ((u >> 16) & 1u);   // round-to-nearest-even
  return (unsigned short)(u >> 16);
}

__device__ __forceinline__ void gll16(const void* g, void* l) {
  __builtin_amdgcn_global_load_lds(
      (const __attribute__((address_space(1))) void*)g,
      (__attribute__((address_space(3))) void*)l, 16, 0, 0);
}

// ---------- f32 -> bf16 conversion (query), vectorized ----------
__global__ __launch_bounds__(256) void cvtq_kernel(const float* __restrict__ src,
                                                   unsigned short* __restrict__ dst) {
  int i = blockIdx.x * 256 + threadIdx.x;
  floatx4 v = ((const floatx4*)src)[i];
  u16x4 o;
  o[0] = f2bf(v[0]); o[1] = f2bf(v[1]); o[2] = f2bf(v[2]); o[3] = f2bf(v[3]);
  ((u16x4*)dst)[i] = o;
}

// ---------- key/value: convert + row-sum zero mask (rows of 512 f32) ----------
__global__ __launch_bounds__(256) void maskcvt_kernel(const float* __restrict__ src,
                                                      unsigned short* __restrict__ dst,
                                                      float* __restrict__ mask) {
  const int w = threadIdx.x >> 6, l = threadIdx.x & 63;
  const size_t row = (size_t)blockIdx.x * 4 + w;
  const float* s = src + row * 512;
  float v[8]; float sum = 0.f;
#pragma unroll
  for (int i = 0; i < 8; ++i) { v[i] = s[l + i * 64]; sum += v[i]; }
#pragma unroll
  for (int d = 1; d < 64; d <<= 1) sum += __shfl_xor(sum, d, 64);
  if (l == 0) mask[row] = (sum == 0.0f) ? 0.f : 1.f;
  unsigned short* dr = dst + row * 512;
#pragma unroll
  for (int i = 0; i < 8; ++i) dr[l + i * 64] = f2bf(v[i]);
}

// ---------- weight transpose + convert: W[K][1024] f32 -> Wt[1024][K] bf16 ----------
__global__ __launch_bounds__(256) void wtt_kernel(const float* __restrict__ W,
                                                  unsigned short* __restrict__ Wt,
                                                  int K, float scale) {
  __shared__ float tile[32][33];
  const int tx = threadIdx.x, ty = threadIdx.y;
  const int n_ = blockIdx.x * 32 + tx;
  const int k0 = blockIdx.y * 32;
#pragma unroll
  for (int i = ty; i < 32; i += 8) tile[i][tx] = W[(size_t)(k0 + i) * 1024 + n_];
  __syncthreads();
  const int k_ = k0 + tx;
#pragma unroll
  for (int i = ty; i < 32; i += 8)
    Wt[(size_t)(blockIdx.x * 32 + i) * K + k_] = f2bf(tile[tx][i] * scale);
}

// ---------- GEMM: C[M][N] = A[M][K](bf16) @ Wt[N][K]^T(bf16) + bias, 128x128 tile ----------
// MASKF: multiply rows by mask[m]; VT: store transposed per-batch [b][n][s] (for V);
// OF32: f32 output (final projection), else bf16.
template <int MASKF, int VT, int OF32>
__global__ __launch_bounds__(256) void gemm_bt_kernel(
    const unsigned short* __restrict__ A, const unsigned short* __restrict__ Bt,
    const float* __restrict__ bias, const float* __restrict__ mask,
    void* __restrict__ outp, int M, int N, int K, float bscale) {
  __shared__ __align__(16) unsigned short As[2][128 * 32];
  __shared__ __align__(16) unsigned short Bs[2][128 * 32];
  const int t = threadIdx.x;
  const int w = t >> 6, l = t & 63, g = l >> 4, lm = l & 15;
  const int m0 = blockIdx.y * 128, n0 = blockIdx.x * 128;
  const int wm = w >> 1, wn = w & 1;
  floatx4 acc[4][4] = {};

  const int NK = K >> 5;
  auto stage = [&](int kt, int buf) {
#pragma unroll
    for (int issue = 0; issue < 2; ++issue) {
      const int tt = issue * 256 + t;
      gll16(A + (size_t)(m0 + (tt >> 2)) * K + kt * 32 + (tt & 3) * 8,
            (void*)((char*)&As[buf][0] + issue * 4096 + w * 1024));
      gll16(Bt + (size_t)(n0 + (tt >> 2)) * K + kt * 32 + (tt & 3) * 8,
            (void*)((char*)&Bs[buf][0] + issue * 4096 + w * 1024));
    }
  };

  stage(0, 0);
  int cur = 0;
  for (int kt = 0; kt < NK; ++kt) {
    __syncthreads();                       // buf[cur] staged; all waves done with buf[cur^1]
    if (kt + 1 < NK) stage(kt + 1, cur ^ 1);  // async prefetch overlaps compute
    const unsigned short* Ab = &As[cur][0];
    const unsigned short* Bb = &Bs[cur][0];
    bf16x8 af[4], bfr[4];
#pragma unroll
    for (int mr = 0; mr < 4; ++mr)
      af[mr] = *(const bf16x8*)(Ab + (wm * 64 + mr * 16 + lm) * 32 + g * 8);
#pragma unroll
    for (int nf = 0; nf < 4; ++nf)
      bfr[nf] = *(const bf16x8*)(Bb + (wn * 64 + nf * 16 + lm) * 32 + g * 8);
#pragma unroll
    for (int mr = 0; mr < 4; ++mr)
#pragma unroll
      for (int nf = 0; nf < 4; ++nf)
        acc[mr][nf] = MFMA16(af[mr], bfr[nf], acc[mr][nf]);
    cur ^= 1;
  }

#pragma unroll
  for (int nf = 0; nf < 4; ++nf) {
    const int n = n0 + wn * 64 + nf * 16 + lm;
    const float bv = bias[n] * bscale;
#pragma unroll
    for (int mr = 0; mr < 4; ++mr) {
      const int mb = m0 + wm * 64 + mr * 16 + g * 4;
      if (VT) {
        u16x4 pk;
#pragma unroll
        for (int j = 0; j < 4; ++j) {
          float v = acc[mr][nf][j] + bv;
          if (MASKF) v *= mask[mb + j];
          pk[j] = f2bf(v);
        }
        const int bb = mb >> 11;       // m / 2048
        const int s = mb & 2047;       // m % 2048
        *(u16x4*)((unsigned short*)outp + ((size_t)bb * 1024 + n) * 2048 + s) = pk;
      } else {
#pragma unroll
        for (int j = 0; j < 4; ++j) {
          float v = acc[mr][nf][j] + bv;
          if (MASKF) v *= mask[mb + j];
          if (OF32) ((float*)outp)[(size_t)(mb + j) * N + n] = v;
          else ((unsigned short*)outp)[(size_t)(mb + j) * N + n] = f2bf(v);
        }
      }
    }
  }
}

// ---------- flash attention: block = (b,h) x 128 Q rows; 4 waves x 32 rows ----------
// Qp pre-scaled by 1/sqrt(dk). Kp natural [b*S+kv][1024]; Vt transposed [b][n][kv].
__global__ __launch_bounds__(256) void flash_kernel(
    const unsigned short* __restrict__ Qp, const unsigned short* __restrict__ Kp,
    const unsigned short* __restrict__ Vt, unsigned short* __restrict__ Ctx) {
  __shared__ __align__(16) unsigned short Ks[2][64 * 64];
  __shared__ __align__(16) unsigned short Vs[2][64 * 64];
  __shared__ __align__(16) unsigned short Ps[4][32 * 64];
  const int t = threadIdx.x, w = t >> 6, l = t & 63, g = l >> 4, lm = l & 15;
  const int qt = blockIdx.x, bh = blockIdx.y;
  const int b = bh >> 4, h = bh & 15;
  const int q0 = qt * 128 + w * 32;
  const size_t qgr = (size_t)b * 2048 + q0;

  bf16x8 qf[2][2];  // Q A-fragments, hoisted
#pragma unroll
  for (int mr = 0; mr < 2; ++mr)
#pragma unroll
    for (int kf = 0; kf < 2; ++kf)
      qf[mr][kf] = *(const bf16x8*)(Qp + (qgr + mr * 16 + lm) * 1024 + h * 64 + kf * 32 + g * 8);

  floatx4 oacc[2][4] = {};
  float mx[2][4], sm[2][4];
#pragma unroll
  for (int mr = 0; mr < 2; ++mr)
#pragma unroll
    for (int jj = 0; jj < 4; ++jj) { mx[mr][jj] = -1e30f; sm[mr][jj] = 0.f; }

  // XOR-swizzled staging: stored chunk sc holds data chunk sc ^ (row&7)
  auto stage = [&](int tile, int buf) {
#pragma unroll
    for (int issue = 0; issue < 2; ++issue) {
      const int tt = issue * 256 + t;
      const int row = tt >> 3;
      const int c = (tt & 7) ^ (row & 7);
      gll16(Kp + ((size_t)b * 2048 + tile * 64 + row) * 1024 + h * 64 + c * 8,
            (void*)((char*)&Ks[buf][0] + issue * 4096 + w * 1024));
      gll16(Vt + ((size_t)b * 1024 + h * 64 + row) * 2048 + tile * 64 + c * 8,
            (void*)((char*)&Vs[buf][0] + issue * 4096 + w * 1024));
    }
  };

  stage(0, 0);
  int cur = 0;
  for (int tile = 0; tile < 32; ++tile) {
    __syncthreads();
    if (tile + 1 < 32) stage(tile + 1, cur ^ 1);

    // S = Q K^T  (K rows read as B-fragments of K^T)
    floatx4 sacc[2][4] = {};
#pragma unroll
    for (int kf = 0; kf < 2; ++kf) {
      bf16x8 kfr[4];
#pragma unroll
      for (int nf = 0; nf < 4; ++nf) {
        const int row = nf * 16 + lm;
        kfr[nf] = *(const bf16x8*)(&Ks[cur][row * 64 + (((kf * 4 + g) ^ (row & 7)) * 8)]);
      }
#pragma unroll
      for (int mr = 0; mr < 2; ++mr)
#pragma unroll
        for (int nf = 0; nf < 4; ++nf)
          sacc[mr][nf] = MFMA16(qf[mr][kf], kfr[nf], sacc[mr][nf]);
    }

    // online softmax; row r = mr*16 + g*4 + jj, cols spread over 16 lanes
#pragma unroll
    for (int mr = 0; mr < 2; ++mr) {
#pragma unroll
      for (int jj = 0; jj < 4; ++jj) {
        float v = fmaxf(fmaxf(sacc[mr][0][jj], sacc[mr][1][jj]),
                        fmaxf(sacc[mr][2][jj], sacc[mr][3][jj]));
#pragma unroll
        for (int d = 1; d < 16; d <<= 1) v = fmaxf(v, __shfl_xor(v, d, 64));
        const float mnew = fmaxf(mx[mr][jj], v);
        const float corr = exp2f((mx[mr][jj] - mnew) * 1.44269504f);
        mx[mr][jj] = mnew;
        float ps = 0.f;
#pragma unroll
        for (int nf = 0; nf < 4; ++nf) {
          const float p = exp2f((sacc[mr][nf][jj] - mnew) * 1.44269504f);
          sacc[mr][nf][jj] = p; ps += p;
        }
#pragma unroll
        for (int d = 1; d < 16; d <<= 1) ps += __shfl_xor(ps, d, 64);
        sm[mr][jj] = sm[mr][jj] * corr + ps;
#pragma unroll
        for (int df = 0; df < 4; ++df) oacc[mr][df][jj] *= corr;
      }
    }

    // P (C-layout) -> per-wave LDS (swizzled), then re-read as A-fragments
#pragma unroll
    for (int mr = 0; mr < 2; ++mr)
#pragma unroll
      for (int nf = 0; nf < 4; ++nf)
#pragma unroll
        for (int jj = 0; jj < 4; ++jj) {
          const int row = mr * 16 + g * 4 + jj;
          const int col = nf * 16 + lm;
          Ps[w][row * 64 + (((col >> 3) ^ (row & 7)) * 8) + (col & 7)] = f2bf(sacc[mr][nf][jj]);
        }

    // O += P @ Vt^T  (Vt rows read as B-fragments)
#pragma unroll
    for (int kf = 0; kf < 2; ++kf) {
      bf16x8 pfr[2], vfr[4];
#pragma unroll
      for (int mr = 0; mr < 2; ++mr) {
        const int row = mr * 16 + lm;
        pfr[mr] = *(const bf16x8*)(&Ps[w][row * 64 + (((kf * 4 + g) ^ (row & 7)) * 8)]);
      }
#pragma unroll
      for (int df = 0; df < 4; ++df) {
        const int row = df * 16 + lm;
        vfr[df] = *(const bf16x8*)(&Vs[cur][row * 64 + (((kf * 4 + g) ^ (row & 7)) * 8)]);
      }
#pragma unroll
      for (int mr = 0; mr < 2; ++mr)
#pragma unroll
        for (int df = 0; df < 4; ++df)
          oacc[mr][df] = MFMA16(pfr[mr], vfr[df], oacc[mr][df]);
    }
    cur ^= 1;
  }

#pragma unroll
  for (int mr = 0; mr < 2; ++mr)
#pragma unroll
    for (int jj = 0; jj < 4; ++jj) {
      const float inv = 1.f / sm[mr][jj];
      const size_t grow = (qgr + mr * 16 + g * 4 + jj) * 1024 + h * 64;
#pragma unroll
      for (int df = 0; df < 4; ++df)
        Ctx[grow + df * 16 + lm] = f2bf(oacc[mr][df][jj] * inv);
    }
}

extern "C" void kernel_launch(void* const* d_in, const int* in_sizes, int n_in,
                              void* d_out, int out_size, void* d_ws, size_t ws_size,
                              hipStream_t stream) {
  const float* query = (const float*)d_in[0];
  const float* key   = (const float*)d_in[1];
  const float* value = (const float*)d_in[2];
  const float* Wq = (const float*)d_in[3];
  const float* bq = (const float*)d_in[4];
  const float* Wk = (const float*)d_in[5];
  const float* bk = (const float*)d_in[6];
  const float* Wv = (const float*)d_in[7];
  const float* bv = (const float*)d_in[8];
  const float* Wo = (const float*)d_in[9];
  const float* bo = (const float*)d_in[10];

  char* ws = (char*)d_ws;
  unsigned short* qbf = (unsigned short*)ws;  ws += (size_t)8192 * 1024 * 2;
  unsigned short* kbf = (unsigned short*)ws;  ws += (size_t)8192 * 512 * 2;
  unsigned short* vbf = (unsigned short*)ws;  ws += (size_t)8192 * 512 * 2;
  unsigned short* Wqt = (unsigned short*)ws;  ws += (size_t)1024 * 1024 * 2;
  unsigned short* Wkt = (unsigned short*)ws;  ws += (size_t)1024 * 512 * 2;
  unsigned short* Wvt = (unsigned short*)ws;  ws += (size_t)1024 * 512 * 2;
  unsigned short* Wot = (unsigned short*)ws;  ws += (size_t)1024 * 1024 * 2;
  unsigned short* Qp  = (unsigned short*)ws;  ws += (size_t)8192 * 1024 * 2;
  unsigned short* Kp  = (unsigned short*)ws;  ws += (size_t)8192 * 1024 * 2;
  unsigned short* Vtp = (unsigned short*)ws;  ws += (size_t)8192 * 1024 * 2;
  unsigned short* Ctx = (unsigned short*)ws;  ws += (size_t)8192 * 1024 * 2;
  float* maskK = (float*)ws;                  ws += (size_t)8192 * 4;
  float* maskV = (float*)ws;                  ws += (size_t)8192 * 4;

  cvtq_kernel<<<8192, 256, 0, stream>>>(query, qbf);
  maskcvt_kernel<<<2048, 256, 0, stream>>>(key, kbf, maskK);
  maskcvt_kernel<<<2048, 256, 0, stream>>>(value, vbf, maskV);
  // fold 1/sqrt(64) into Wq (and bq via bscale)
  wtt_kernel<<<dim3(32, 32), dim3(32, 8), 0, stream>>>(Wq, Wqt, 1024, 0.125f);
  wtt_kernel<<<dim3(32, 16), dim3(32, 8), 0, stream>>>(Wk, Wkt, 512, 1.0f);
  wtt_kernel<<<dim3(32, 16), dim3(32, 8), 0, stream>>>(Wv, Wvt, 512, 1.0f);
  wtt_kernel<<<dim3(32, 32), dim3(32, 8), 0, stream>>>(Wo, Wot, 1024, 1.0f);

  gemm_bt_kernel<0, 0, 0><<<dim3(8, 64), 256, 0, stream>>>(qbf, Wqt, bq, nullptr, Qp, 8192, 1024, 1024, 0.125f);
  gemm_bt_kernel<1, 0, 0><<<dim3(8, 64), 256, 0, stream>>>(kbf, Wkt, bk, maskK, Kp, 8192, 1024, 512, 1.0f);
  gemm_bt_kernel<1, 1, 0><<<dim3(8, 64), 256, 0, stream>>>(vbf, Wvt, bv, maskV, Vtp, 8192, 1024, 512, 1.0f);

  flash_kernel<<<dim3(16, 64), 256, 0, stream>>>(Qp, Kp, Vtp, Ctx);

  gemm_bt_kernel<0, 0, 1><<<dim3(8, 64), 256, 0, stream>>>(Ctx, Wot, bo, nullptr, d_out, 8192, 1024, 1024, 1.0f);
}

// Round 6
// 301.189 us; speedup vs baseline: 1.2820x; 1.2820x over previous
//
#include <hip/hip_runtime.h>

typedef __attribute__((ext_vector_type(8))) short bf16x8;
typedef __attribute__((ext_vector_type(4))) float floatx4;
typedef __attribute__((ext_vector_type(16))) float floatx16;
typedef __attribute__((ext_vector_type(4))) unsigned short u16x4;

#define MFMA16(a, b, c) __builtin_amdgcn_mfma_f32_16x16x32_bf16(a, b, c, 0, 0, 0)
#define MFMA32(a, b, c) __builtin_amdgcn_mfma_f32_32x32x16_bf16(a, b, c, 0, 0, 0)

__device__ __forceinline__ unsigned short f2bf(float f) {
  unsigned int u = __float_as_uint(f);
  u += 0x7fffu + ((u >> 16) & 1u);   // round-to-nearest-even
  return (unsigned short)(u >> 16);
}

__device__ __forceinline__ void gll16(const void* g, void* l) {
  __builtin_amdgcn_global_load_lds(
      (const __attribute__((address_space(1))) void*)g,
      (__attribute__((address_space(3))) void*)l, 16, 0, 0);
}

// ---------- f32 -> bf16 conversion (query), vectorized ----------
__global__ __launch_bounds__(256) void cvtq_kernel(const float* __restrict__ src,
                                                   unsigned short* __restrict__ dst) {
  int i = blockIdx.x * 256 + threadIdx.x;
  floatx4 v = ((const floatx4*)src)[i];
  u16x4 o;
  o[0] = f2bf(v[0]); o[1] = f2bf(v[1]); o[2] = f2bf(v[2]); o[3] = f2bf(v[3]);
  ((u16x4*)dst)[i] = o;
}

// ---------- key/value: convert + row-sum zero mask (rows of 512 f32) ----------
__global__ __launch_bounds__(256) void maskcvt_kernel(const float* __restrict__ src,
                                                      unsigned short* __restrict__ dst,
                                                      float* __restrict__ mask) {
  const int w = threadIdx.x >> 6, l = threadIdx.x & 63;
  const size_t row = (size_t)blockIdx.x * 4 + w;
  const float* s = src + row * 512;
  float v[8]; float sum = 0.f;
#pragma unroll
  for (int i = 0; i < 8; ++i) { v[i] = s[l + i * 64]; sum += v[i]; }
#pragma unroll
  for (int d = 1; d < 64; d <<= 1) sum += __shfl_xor(sum, d, 64);
  if (l == 0) mask[row] = (sum == 0.0f) ? 0.f : 1.f;
  unsigned short* dr = dst + row * 512;
#pragma unroll
  for (int i = 0; i < 8; ++i) dr[l + i * 64] = f2bf(v[i]);
}

// ---------- weight transpose + convert: W[K][1024] f32 -> Wt[1024][K] bf16 ----------
__global__ __launch_bounds__(256) void wtt_kernel(const float* __restrict__ W,
                                                  unsigned short* __restrict__ Wt,
                                                  int K, float scale) {
  __shared__ float tile[32][33];
  const int tx = threadIdx.x, ty = threadIdx.y;
  const int n_ = blockIdx.x * 32 + tx;
  const int k0 = blockIdx.y * 32;
#pragma unroll
  for (int i = ty; i < 32; i += 8) tile[i][tx] = W[(size_t)(k0 + i) * 1024 + n_];
  __syncthreads();
  const int k_ = k0 + tx;
#pragma unroll
  for (int i = ty; i < 32; i += 8)
    Wt[(size_t)(blockIdx.x * 32 + i) * K + k_] = f2bf(tile[tx][i] * scale);
}

// ---------- GEMM: C[M][N] = A[M][K](bf16) @ Wt[N][K]^T(bf16) + bias, 128x128 tile ----------
template <int MASKF, int VT, int OF32>
__global__ __launch_bounds__(256) void gemm_bt_kernel(
    const unsigned short* __restrict__ A, const unsigned short* __restrict__ Bt,
    const float* __restrict__ bias, const float* __restrict__ mask,
    void* __restrict__ outp, int M, int N, int K, float bscale) {
  __shared__ __align__(16) unsigned short As[2][128 * 32];
  __shared__ __align__(16) unsigned short Bs[2][128 * 32];
  const int t = threadIdx.x;
  const int w = t >> 6, l = t & 63, g = l >> 4, lm = l & 15;
  const int m0 = blockIdx.y * 128, n0 = blockIdx.x * 128;
  const int wm = w >> 1, wn = w & 1;
  floatx4 acc[4][4] = {};

  const int NK = K >> 5;
  auto stage = [&](int kt, int buf) {
#pragma unroll
    for (int issue = 0; issue < 2; ++issue) {
      const int tt = issue * 256 + t;
      gll16(A + (size_t)(m0 + (tt >> 2)) * K + kt * 32 + (tt & 3) * 8,
            (void*)((char*)&As[buf][0] + issue * 4096 + w * 1024));
      gll16(Bt + (size_t)(n0 + (tt >> 2)) * K + kt * 32 + (tt & 3) * 8,
            (void*)((char*)&Bs[buf][0] + issue * 4096 + w * 1024));
    }
  };

  stage(0, 0);
  int cur = 0;
  for (int kt = 0; kt < NK; ++kt) {
    __syncthreads();
    if (kt + 1 < NK) stage(kt + 1, cur ^ 1);
    const unsigned short* Ab = &As[cur][0];
    const unsigned short* Bb = &Bs[cur][0];
    bf16x8 af[4], bfr[4];
#pragma unroll
    for (int mr = 0; mr < 4; ++mr)
      af[mr] = *(const bf16x8*)(Ab + (wm * 64 + mr * 16 + lm) * 32 + g * 8);
#pragma unroll
    for (int nf = 0; nf < 4; ++nf)
      bfr[nf] = *(const bf16x8*)(Bb + (wn * 64 + nf * 16 + lm) * 32 + g * 8);
#pragma unroll
    for (int mr = 0; mr < 4; ++mr)
#pragma unroll
      for (int nf = 0; nf < 4; ++nf)
        acc[mr][nf] = MFMA16(af[mr], bfr[nf], acc[mr][nf]);
    cur ^= 1;
  }

#pragma unroll
  for (int nf = 0; nf < 4; ++nf) {
    const int n = n0 + wn * 64 + nf * 16 + lm;
    const float bv = bias[n] * bscale;
#pragma unroll
    for (int mr = 0; mr < 4; ++mr) {
      const int mb = m0 + wm * 64 + mr * 16 + g * 4;
      if (VT) {
        u16x4 pk;
#pragma unroll
        for (int j = 0; j < 4; ++j) {
          float v = acc[mr][nf][j] + bv;
          if (MASKF) v *= mask[mb + j];
          pk[j] = f2bf(v);
        }
        const int bb = mb >> 11;
        const int s = mb & 2047;
        *(u16x4*)((unsigned short*)outp + ((size_t)bb * 1024 + n) * 2048 + s) = pk;
      } else {
#pragma unroll
        for (int j = 0; j < 4; ++j) {
          float v = acc[mr][nf][j] + bv;
          if (MASKF) v *= mask[mb + j];
          if (OF32) ((float*)outp)[(size_t)(mb + j) * N + n] = v;
          else ((unsigned short*)outp)[(size_t)(mb + j) * N + n] = f2bf(v);
        }
      }
    }
  }
}

// ---------- flash attention, swapped-QK^T 32x32, P routed through LDS ----------
// Block = (b,h) x 128 Q rows; 4 waves x 32 q-rows. KVBLK=64.
// S^T = mfma32(A=K, B=Q): lane (q=ln, hi) holds S^T[kv=c*32+crow(r,hi)][q=ln]
// -> softmax fully in-register (31 fmax + 1 shfl_xor(32)); state is per q=ln.
// P stored to per-wave LDS as P[q][kv] (manual bf16 pair-pack, chunk-XOR swz),
// re-read as P^T B-fragments. O^T = mfma32(A=V^T, B=P^T): D col = q = ln ->
// corr rescale and 1/sm are lane-local. Epilogue: LDS transpose, coalesced store.
// NOTE: no cvt_pk / permlane / amdgcn exp2 / rcp builtins — every cross-lane or
// pack step here is either HW-verified (m74/m101 layouts, round-1-verified
// staging swizzle) or cancellation-immune (consistent A/B k-maps).
__global__ __launch_bounds__(256) void flash_kernel(
    const unsigned short* __restrict__ Qp, const unsigned short* __restrict__ Kp,
    const unsigned short* __restrict__ Vt, unsigned short* __restrict__ Ctx) {
  __shared__ __align__(16) unsigned short Ks[2][64 * 64];
  __shared__ __align__(16) unsigned short Vs[2][64 * 64];
  __shared__ __align__(16) unsigned short Ps[4][32 * 64];
  const int t = threadIdx.x, w = t >> 6, l = t & 63, hi = l >> 5, ln = l & 31;

  // T1: bijective XCD swizzle (nwg=1024, %8==0): each XCD owns 8 contiguous bh
  const int orig = blockIdx.y * 16 + blockIdx.x;
  const int lin = (orig & 7) * 128 + (orig >> 3);
  const int bh = lin >> 4, qt = lin & 15;
  const int b = bh >> 4, h = bh & 15;
  const int q0 = qt * 128 + w * 32;
  const size_t qg = (size_t)b * 2048 + q0;

  // Q fragments (B-operand): lane ln = q, k = kc*16 + hi*8 + j
  bf16x8 qf[4];
#pragma unroll
  for (int kc = 0; kc < 4; ++kc)
    qf[kc] = *(const bf16x8*)(Qp + (qg + ln) * 1024 + h * 64 + kc * 16 + hi * 8);

  floatx16 oacc[2] = {};
  float mx = -3.0e38f, sm = 0.f;

  // XOR-swizzled staging: LDS slot cs of row holds global chunk cs^(row&7)
  auto stage = [&](int tile, int buf) {
#pragma unroll
    for (int issue = 0; issue < 2; ++issue) {
      const int tt = issue * 256 + t;
      const int row = tt >> 3;
      const int c = (tt & 7) ^ (row & 7);
      gll16(Kp + ((size_t)b * 2048 + tile * 64 + row) * 1024 + h * 64 + c * 8,
            (void*)((char*)&Ks[buf][0] + issue * 4096 + w * 1024));
      gll16(Vt + ((size_t)b * 1024 + h * 64 + row) * 2048 + tile * 64 + c * 8,
            (void*)((char*)&Vs[buf][0] + issue * 4096 + w * 1024));
    }
  };

  stage(0, 0);
  int cur = 0;
  for (int tile = 0; tile < 32; ++tile) {
    __syncthreads();
    if (tile + 1 < 32) stage(tile + 1, cur ^ 1);

    // S^T[kv][q], two 32-kv chunks, accumulate over 4 k-chunks of 16
    floatx16 sacc[2] = {};
#pragma unroll
    for (int c = 0; c < 2; ++c) {
#pragma unroll
      for (int kc = 0; kc < 4; ++kc) {
        const int row = c * 32 + ln;
        bf16x8 kf = *(const bf16x8*)(&Ks[cur][row * 64 + (((kc * 2 + hi) ^ (row & 7)) * 8)]);
        sacc[c] = MFMA32(kf, qf[kc], sacc[c]);
      }
    }

    // online softmax, in-register (Q pre-scaled by log2e/sqrt(dk))
    float pm = sacc[0][0];
#pragma unroll
    for (int r = 1; r < 16; ++r) pm = fmaxf(pm, sacc[0][r]);
#pragma unroll
    for (int r = 0; r < 16; ++r) pm = fmaxf(pm, sacc[1][r]);
    pm = fmaxf(pm, __shfl_xor(pm, 32, 64));
    const float mnew = fmaxf(mx, pm);
    const float corr = exp2f(mx - mnew);
    mx = mnew;
    float ps = 0.f;
#pragma unroll
    for (int c = 0; c < 2; ++c)
#pragma unroll
      for (int r = 0; r < 16; ++r) {
        const float p = exp2f(sacc[c][r] - mnew);
        sacc[c][r] = p;
        ps += p;
      }
    ps += __shfl_xor(ps, 32, 64);
    sm = sm * corr + ps;
    // O^T rescale: col q = ln -> corr is lane-local
#pragma unroll
    for (int dc = 0; dc < 2; ++dc)
#pragma unroll
      for (int r = 0; r < 16; ++r) oacc[dc][r] *= corr;

    // P -> per-wave LDS as P[q=ln][kv], manual bf16 pair-pack (kv, kv+1),
    // chunk-XOR swizzle by row (q&7). crow(r)+1 == crow(r+1) for even r.
#pragma unroll
    for (int c = 0; c < 2; ++c)
#pragma unroll
      for (int r = 0; r < 16; r += 2) {
        const int kv = c * 32 + (r & 3) + 8 * (r >> 2) + 4 * hi;
        const unsigned int pk = (unsigned int)f2bf(sacc[c][r]) |
                                ((unsigned int)f2bf(sacc[c][r + 1]) << 16);
        *(unsigned int*)(&Ps[w][ln * 64 + (((kv >> 3) ^ (ln & 7)) * 8) + (kv & 7)]) = pk;
      }
    // same-wave RAW on LDS: compiler inserts lgkmcnt waits

    // O^T[d][q] += V^T·P^T : A = V^T rows (m=d), B = P^T (col q = ln)
#pragma unroll
    for (int dc = 0; dc < 2; ++dc) {
#pragma unroll
      for (int ks = 0; ks < 4; ++ks) {
        const int row = dc * 32 + ln;
        bf16x8 vf = *(const bf16x8*)(&Vs[cur][row * 64 + (((ks * 2 + hi) ^ (row & 7)) * 8)]);
        bf16x8 pfr = *(const bf16x8*)(&Ps[w][ln * 64 + (((ks * 2 + hi) ^ (ln & 7)) * 8)]);
        oacc[dc] = MFMA32(vf, pfr, oacc[dc]);
      }
    }
    cur ^= 1;
  }

  // epilogue: lane holds O^T[d = dc*32+crow(r,hi)][q = ln]; inv is lane-local.
  // Transpose via per-wave LDS (reuse Ks after barrier), then coalesced store.
  __syncthreads();
  const float inv = 1.f / sm;
  unsigned short* lds_o = &Ks[0][0] + w * 2048;  // 4KB per wave: O[q=32][d=64]
#pragma unroll
  for (int dc = 0; dc < 2; ++dc)
#pragma unroll
    for (int r = 0; r < 16; r += 2) {
      const int d = dc * 32 + (r & 3) + 8 * (r >> 2) + 4 * hi;  // even; d+1 next
      const unsigned int pk = (unsigned int)f2bf(oacc[dc][r] * inv) |
                              ((unsigned int)f2bf(oacc[dc][r + 1] * inv) << 16);
      *(unsigned int*)(&lds_o[ln * 64 + (((d >> 3) ^ (ln & 7)) * 8) + (d & 7)]) = pk;
    }
  __builtin_amdgcn_s_waitcnt(0);  // lgkmcnt(0): same-wave LDS RAW
#pragma unroll
  for (int i = 0; i < 4; ++i) {
    const int q = i * 8 + (l >> 3);
    const int cd = l & 7;
    bf16x8 vv = *(const bf16x8*)(&lds_o[q * 64 + ((cd ^ (q & 7)) * 8)]);
    *(bf16x8*)(&Ctx[(qg + q) * 1024 + h * 64 + cd * 8]) = vv;
  }
}

extern "C" void kernel_launch(void* const* d_in, const int* in_sizes, int n_in,
                              void* d_out, int out_size, void* d_ws, size_t ws_size,
                              hipStream_t stream) {
  const float* query = (const float*)d_in[0];
  const float* key   = (const float*)d_in[1];
  const float* value = (const float*)d_in[2];
  const float* Wq = (const float*)d_in[3];
  const float* bq = (const float*)d_in[4];
  const float* Wk = (const float*)d_in[5];
  const float* bk = (const float*)d_in[6];
  const float* Wv = (const float*)d_in[7];
  const float* bv = (const float*)d_in[8];
  const float* Wo = (const float*)d_in[9];
  const float* bo = (const float*)d_in[10];

  char* ws = (char*)d_ws;
  unsigned short* qbf = (unsigned short*)ws;  ws += (size_t)8192 * 1024 * 2;
  unsigned short* kbf = (unsigned short*)ws;  ws += (size_t)8192 * 512 * 2;
  unsigned short* vbf = (unsigned short*)ws;  ws += (size_t)8192 * 512 * 2;
  unsigned short* Wqt = (unsigned short*)ws;  ws += (size_t)1024 * 1024 * 2;
  unsigned short* Wkt = (unsigned short*)ws;  ws += (size_t)1024 * 512 * 2;
  unsigned short* Wvt = (unsigned short*)ws;  ws += (size_t)1024 * 512 * 2;
  unsigned short* Wot = (unsigned short*)ws;  ws += (size_t)1024 * 1024 * 2;
  unsigned short* Qp  = (unsigned short*)ws;  ws += (size_t)8192 * 1024 * 2;
  unsigned short* Kp  = (unsigned short*)ws;  ws += (size_t)8192 * 1024 * 2;
  unsigned short* Vtp = (unsigned short*)ws;  ws += (size_t)8192 * 1024 * 2;
  unsigned short* Ctx = (unsigned short*)ws;  ws += (size_t)8192 * 1024 * 2;
  float* maskK = (float*)ws;                  ws += (size_t)8192 * 4;
  float* maskV = (float*)ws;                  ws += (size_t)8192 * 4;

  cvtq_kernel<<<8192, 256, 0, stream>>>(query, qbf);
  maskcvt_kernel<<<2048, 256, 0, stream>>>(key, kbf, maskK);
  maskcvt_kernel<<<2048, 256, 0, stream>>>(value, vbf, maskV);
  // fold log2(e)/sqrt(64) into Wq/bq so flash works in exp2 domain
  const float QS = 0.125f * 1.44269504f;
  wtt_kernel<<<dim3(32, 32), dim3(32, 8), 0, stream>>>(Wq, Wqt, 1024, QS);
  wtt_kernel<<<dim3(32, 16), dim3(32, 8), 0, stream>>>(Wk, Wkt, 512, 1.0f);
  wtt_kernel<<<dim3(32, 16), dim3(32, 8), 0, stream>>>(Wv, Wvt, 512, 1.0f);
  wtt_kernel<<<dim3(32, 32), dim3(32, 8), 0, stream>>>(Wo, Wot, 1024, 1.0f);

  gemm_bt_kernel<0, 0, 0><<<dim3(8, 64), 256, 0, stream>>>(qbf, Wqt, bq, nullptr, Qp, 8192, 1024, 1024, QS);
  gemm_bt_kernel<1, 0, 0><<<dim3(8, 64), 256, 0, stream>>>(kbf, Wkt, bk, maskK, Kp, 8192, 1024, 512, 1.0f);
  gemm_bt_kernel<1, 1, 0><<<dim3(8, 64), 256, 0, stream>>>(vbf, Wvt, bv, maskV, Vtp, 8192, 1024, 512, 1.0f);

  flash_kernel<<<dim3(16, 64), 256, 0, stream>>>(Qp, Kp, Vtp, Ctx);

  gemm_bt_kernel<0, 0, 1><<<dim3(8, 64), 256, 0, stream>>>(Ctx, Wot, bo, nullptr, d_out, 8192, 1024, 1024, 1.0f);
}

// Round 8
// 288.058 us; speedup vs baseline: 1.3405x; 1.0456x over previous
//
#include <hip/hip_runtime.h>
#include <hip/hip_bf16.h>

typedef __attribute__((ext_vector_type(8))) short bf16x8;
typedef __attribute__((ext_vector_type(4))) float floatx4;
typedef __attribute__((ext_vector_type(16))) float floatx16;
typedef __attribute__((ext_vector_type(4))) unsigned short u16x4;
typedef __attribute__((ext_vector_type(4))) int intx4;

#define MFMA16(a, b, c) __builtin_amdgcn_mfma_f32_16x16x32_bf16(a, b, c, 0, 0, 0)
#define MFMA32(a, b, c) __builtin_amdgcn_mfma_f32_32x32x16_bf16(a, b, c, 0, 0, 0)

__device__ __forceinline__ unsigned short f2bf(float f) {
  unsigned int u = __float_as_uint(f);
  u += 0x7fffu + ((u >> 16) & 1u);   // round-to-nearest-even
  return (unsigned short)(u >> 16);
}

// compiler-chosen packed f32->bf16x2 (low = first arg)
__device__ __forceinline__ unsigned int pkbf2(float lo, float hi) {
  __hip_bfloat162 h = __float22bfloat162_rn(float2{lo, hi});
  unsigned int r;
  __builtin_memcpy(&r, &h, 4);
  return r;
}

__device__ __forceinline__ void gll16(const void* g, void* l) {
  __builtin_amdgcn_global_load_lds(
      (const __attribute__((address_space(1))) void*)g,
      (__attribute__((address_space(3))) void*)l, 16, 0, 0);
}

// ---------- f32 -> bf16 conversion (query), vectorized ----------
__global__ __launch_bounds__(256) void cvtq_kernel(const float* __restrict__ src,
                                                   unsigned short* __restrict__ dst) {
  int i = blockIdx.x * 256 + threadIdx.x;
  floatx4 v = ((const floatx4*)src)[i];
  u16x4 o;
  o[0] = f2bf(v[0]); o[1] = f2bf(v[1]); o[2] = f2bf(v[2]); o[3] = f2bf(v[3]);
  ((u16x4*)dst)[i] = o;
}

// ---------- key/value: convert + row-sum zero mask (rows of 512 f32) ----------
__global__ __launch_bounds__(256) void maskcvt_kernel(const float* __restrict__ src,
                                                      unsigned short* __restrict__ dst,
                                                      float* __restrict__ mask) {
  const int w = threadIdx.x >> 6, l = threadIdx.x & 63;
  const size_t row = (size_t)blockIdx.x * 4 + w;
  const float* s = src + row * 512;
  float v[8]; float sum = 0.f;
#pragma unroll
  for (int i = 0; i < 8; ++i) { v[i] = s[l + i * 64]; sum += v[i]; }
#pragma unroll
  for (int d = 1; d < 64; d <<= 1) sum += __shfl_xor(sum, d, 64);
  if (l == 0) mask[row] = (sum == 0.0f) ? 0.f : 1.f;
  unsigned short* dr = dst + row * 512;
#pragma unroll
  for (int i = 0; i < 8; ++i) dr[l + i * 64] = f2bf(v[i]);
}

// ---------- weight transpose + convert: W[K][1024] f32 -> Wt[1024][K] bf16 ----------
__global__ __launch_bounds__(256) void wtt_kernel(const float* __restrict__ W,
                                                  unsigned short* __restrict__ Wt,
                                                  int K, float scale) {
  __shared__ float tile[32][33];
  const int tx = threadIdx.x, ty = threadIdx.y;
  const int n_ = blockIdx.x * 32 + tx;
  const int k0 = blockIdx.y * 32;
#pragma unroll
  for (int i = ty; i < 32; i += 8) tile[i][tx] = W[(size_t)(k0 + i) * 1024 + n_];
  __syncthreads();
  const int k_ = k0 + tx;
#pragma unroll
  for (int i = ty; i < 32; i += 8)
    Wt[(size_t)(blockIdx.x * 32 + i) * K + k_] = f2bf(tile[tx][i] * scale);
}

// ---------- GEMM: C[M][N] = A[M][K](bf16) @ Wt[N][K]^T(bf16) + bias, 128x128 tile ----------
template <int MASKF, int VT, int OF32>
__global__ __launch_bounds__(256) void gemm_bt_kernel(
    const unsigned short* __restrict__ A, const unsigned short* __restrict__ Bt,
    const float* __restrict__ bias, const float* __restrict__ mask,
    void* __restrict__ outp, int M, int N, int K, float bscale) {
  __shared__ __align__(16) unsigned short As[2][128 * 32];
  __shared__ __align__(16) unsigned short Bs[2][128 * 32];
  const int t = threadIdx.x;
  const int w = t >> 6, l = t & 63, g = l >> 4, lm = l & 15;
  const int m0 = blockIdx.y * 128, n0 = blockIdx.x * 128;
  const int wm = w >> 1, wn = w & 1;
  floatx4 acc[4][4] = {};

  const int NK = K >> 5;
  auto stage = [&](int kt, int buf) {
#pragma unroll
    for (int issue = 0; issue < 2; ++issue) {
      const int tt = issue * 256 + t;
      gll16(A + (size_t)(m0 + (tt >> 2)) * K + kt * 32 + (tt & 3) * 8,
            (void*)((char*)&As[buf][0] + issue * 4096 + w * 1024));
      gll16(Bt + (size_t)(n0 + (tt >> 2)) * K + kt * 32 + (tt & 3) * 8,
            (void*)((char*)&Bs[buf][0] + issue * 4096 + w * 1024));
    }
  };

  stage(0, 0);
  int cur = 0;
  for (int kt = 0; kt < NK; ++kt) {
    __syncthreads();
    if (kt + 1 < NK) stage(kt + 1, cur ^ 1);
    const unsigned short* Ab = &As[cur][0];
    const unsigned short* Bb = &Bs[cur][0];
    bf16x8 af[4], bfr[4];
#pragma unroll
    for (int mr = 0; mr < 4; ++mr)
      af[mr] = *(const bf16x8*)(Ab + (wm * 64 + mr * 16 + lm) * 32 + g * 8);
#pragma unroll
    for (int nf = 0; nf < 4; ++nf)
      bfr[nf] = *(const bf16x8*)(Bb + (wn * 64 + nf * 16 + lm) * 32 + g * 8);
#pragma unroll
    for (int mr = 0; mr < 4; ++mr)
#pragma unroll
      for (int nf = 0; nf < 4; ++nf)
        acc[mr][nf] = MFMA16(af[mr], bfr[nf], acc[mr][nf]);
    cur ^= 1;
  }

#pragma unroll
  for (int nf = 0; nf < 4; ++nf) {
    const int n = n0 + wn * 64 + nf * 16 + lm;
    const float bv = bias[n] * bscale;
#pragma unroll
    for (int mr = 0; mr < 4; ++mr) {
      const int mb = m0 + wm * 64 + mr * 16 + g * 4;
      if (VT) {
        u16x4 pk;
#pragma unroll
        for (int j = 0; j < 4; ++j) {
          float v = acc[mr][nf][j] + bv;
          if (MASKF) v *= mask[mb + j];
          pk[j] = f2bf(v);
        }
        const int bb = mb >> 11;
        const int s = mb & 2047;
        *(u16x4*)((unsigned short*)outp + ((size_t)bb * 1024 + n) * 2048 + s) = pk;
      } else {
#pragma unroll
        for (int j = 0; j < 4; ++j) {
          float v = acc[mr][nf][j] + bv;
          if (MASKF) v *= mask[mb + j];
          if (OF32) ((float*)outp)[(size_t)(mb + j) * N + n] = v;
          else ((unsigned short*)outp)[(size_t)(mb + j) * N + n] = f2bf(v);
        }
      }
    }
  }
}

// ---------- flash attention, swapped-QK^T 32x32, P fully in-register ----------
// Block = (b,h) x 128 Q rows; 4 waves x 32 q-rows. KVBLK=64.
// S^T = mfma32(A=K, B=Q): lane (q=ln, hi) holds S^T[kv=c*32+(r&3)+8*(r>>2)+4hi][q=ln]
// (HW-verified by round-6 pass). Softmax in-register per q=ln, T13 defer-max.
// PV: contraction kv-order chosen = P's NATURAL register order
// (kv = base + (j&3) + 8*(j>>2) + 4*hi for k-slot j, hi = lane half); the
// hi-dependence is absorbed into V's addressing (two ds_read_b64 at +8*hi),
// so P packs are 16 consecutive-register bf16 pairs -- no cross-lane ops, no
// LDS P round-trip. Consistent A/B k-maps => permutation cancels in the sum.
// O^T = mfma32(A=V', B=P^T): D col = q = ln -> corr/1/sm lane-local.
__global__ __launch_bounds__(256) void flash_kernel(
    const unsigned short* __restrict__ Qp, const unsigned short* __restrict__ Kp,
    const unsigned short* __restrict__ Vt, unsigned short* __restrict__ Ctx) {
  __shared__ __align__(16) unsigned short Ks[2][64 * 64];
  __shared__ __align__(16) unsigned short Vs[2][64 * 64];
  const int t = threadIdx.x, w = t >> 6, l = t & 63, hi = l >> 5, ln = l & 31;

  // T1: bijective XCD swizzle (nwg=1024, %8==0): each XCD owns 8 contiguous bh
  const int orig = blockIdx.y * 16 + blockIdx.x;
  const int lin = (orig & 7) * 128 + (orig >> 3);
  const int bh = lin >> 4, qt = lin & 15;
  const int b = bh >> 4, h = bh & 15;
  const int q0 = qt * 128 + w * 32;
  const size_t qg = (size_t)b * 2048 + q0;

  // Q fragments (B-operand): lane ln = q, k = kc*16 + hi*8 + j
  bf16x8 qf[4];
#pragma unroll
  for (int kc = 0; kc < 4; ++kc)
    qf[kc] = *(const bf16x8*)(Qp + (qg + ln) * 1024 + h * 64 + kc * 16 + hi * 8);

  floatx16 oacc[2] = {};
  float mx = -3.0e38f, sm = 0.f;

  // XOR-swizzled staging: LDS slot cs of row holds global chunk cs^(row&7)
  auto stage = [&](int tile, int buf) {
#pragma unroll
    for (int issue = 0; issue < 2; ++issue) {
      const int tt = issue * 256 + t;
      const int row = tt >> 3;
      const int c = (tt & 7) ^ (row & 7);
      gll16(Kp + ((size_t)b * 2048 + tile * 64 + row) * 1024 + h * 64 + c * 8,
            (void*)((char*)&Ks[buf][0] + issue * 4096 + w * 1024));
      gll16(Vt + ((size_t)b * 1024 + h * 64 + row) * 2048 + tile * 64 + c * 8,
            (void*)((char*)&Vs[buf][0] + issue * 4096 + w * 1024));
    }
  };

  stage(0, 0);
  int cur = 0;
  for (int tile = 0; tile < 32; ++tile) {
    __syncthreads();
    if (tile + 1 < 32) stage(tile + 1, cur ^ 1);

    // S^T[kv][q], two 32-kv chunks, accumulate over 4 k-chunks of 16
    floatx16 sacc[2] = {};
#pragma unroll
    for (int c = 0; c < 2; ++c) {
#pragma unroll
      for (int kc = 0; kc < 4; ++kc) {
        const int row = c * 32 + ln;
        bf16x8 kf = *(const bf16x8*)(&Ks[cur][row * 64 + (((kc * 2 + hi) ^ (row & 7)) * 8)]);
        sacc[c] = MFMA32(kf, qf[kc], sacc[c]);
      }
    }

    // online softmax (Q pre-scaled by log2e/sqrt(dk)), T13 defer-max (thr=8)
    float pm = sacc[0][0];
#pragma unroll
    for (int r = 1; r < 16; ++r) pm = fmaxf(pm, sacc[0][r]);
#pragma unroll
    for (int r = 0; r < 16; ++r) pm = fmaxf(pm, sacc[1][r]);
    pm = fmaxf(pm, __shfl_xor(pm, 32, 64));
    if (!__all(pm - mx <= 8.f)) {
      const float mnew = fmaxf(mx, pm);
      const float corr = exp2f(mx - mnew);
      mx = mnew;
      sm *= corr;
#pragma unroll
      for (int dc = 0; dc < 2; ++dc)
#pragma unroll
        for (int r = 0; r < 16; ++r) oacc[dc][r] *= corr;
    }
    float ps = 0.f;
#pragma unroll
    for (int c = 0; c < 2; ++c)
#pragma unroll
      for (int r = 0; r < 16; ++r) {
        const float p = exp2f(sacc[c][r] - mx);
        sacc[c][r] = p;
        ps += p;
      }
    ps += __shfl_xor(ps, 32, 64);
    sm += ps;

    // PV: P packed in natural register order; V read as 2x b64 with +8*hi.
    // k-slot j (lane hi) means kv = 32c + 16h2 + (j&3) + 8*(j>>2) + 4hi on
    // BOTH operands -> permutation cancels.
#pragma unroll
    for (int c = 0; c < 2; ++c)
#pragma unroll
      for (int h2 = 0; h2 < 2; ++h2) {
        intx4 wd;
#pragma unroll
        for (int wj = 0; wj < 4; ++wj)
          wd[wj] = (int)pkbf2(sacc[c][h2 * 8 + 2 * wj], sacc[c][h2 * 8 + 2 * wj + 1]);
        const bf16x8 pf = __builtin_bit_cast(bf16x8, wd);
        const int ch0 = 4 * c + 2 * h2;
#pragma unroll
        for (int dc = 0; dc < 2; ++dc) {
          const int row = dc * 32 + ln;
          const int rb = row * 64;
          const u16x4 lo = *(const u16x4*)(&Vs[cur][rb + ((ch0 ^ (row & 7)) * 8) + 4 * hi]);
          const u16x4 hw = *(const u16x4*)(&Vs[cur][rb + (((ch0 + 1) ^ (row & 7)) * 8) + 4 * hi]);
          bf16x8 vf;
          vf[0] = (short)lo[0]; vf[1] = (short)lo[1]; vf[2] = (short)lo[2]; vf[3] = (short)lo[3];
          vf[4] = (short)hw[0]; vf[5] = (short)hw[1]; vf[6] = (short)hw[2]; vf[7] = (short)hw[3];
          oacc[dc] = MFMA32(vf, pf, oacc[dc]);
        }
      }
    cur ^= 1;
  }

  // epilogue: lane holds O^T[d = dc*32+crow(r,hi)][q = ln]; inv is lane-local.
  // Transpose via per-wave LDS (reuse Ks after barrier), then coalesced store.
  __syncthreads();
  const float inv = 1.f / sm;
  unsigned short* lds_o = &Ks[0][0] + w * 2048;  // 4KB per wave: O[q=32][d=64]
#pragma unroll
  for (int dc = 0; dc < 2; ++dc)
#pragma unroll
    for (int r = 0; r < 16; r += 2) {
      const int d = dc * 32 + (r & 3) + 8 * (r >> 2) + 4 * hi;  // even; d+1 next
      const unsigned int pk = pkbf2(oacc[dc][r] * inv, oacc[dc][r + 1] * inv);
      *(unsigned int*)(&lds_o[ln * 64 + (((d >> 3) ^ (ln & 7)) * 8) + (d & 7)]) = pk;
    }
  __builtin_amdgcn_s_waitcnt(0);  // lgkmcnt(0): same-wave LDS RAW
#pragma unroll
  for (int i = 0; i < 4; ++i) {
    const int q = i * 8 + (l >> 3);
    const int cd = l & 7;
    bf16x8 vv = *(const bf16x8*)(&lds_o[q * 64 + ((cd ^ (q & 7)) * 8)]);
    *(bf16x8*)(&Ctx[(qg + q) * 1024 + h * 64 + cd * 8]) = vv;
  }
}

extern "C" void kernel_launch(void* const* d_in, const int* in_sizes, int n_in,
                              void* d_out, int out_size, void* d_ws, size_t ws_size,
                              hipStream_t stream) {
  const float* query = (const float*)d_in[0];
  const float* key   = (const float*)d_in[1];
  const float* value = (const float*)d_in[2];
  const float* Wq = (const float*)d_in[3];
  const float* bq = (const float*)d_in[4];
  const float* Wk = (const float*)d_in[5];
  const float* bk = (const float*)d_in[6];
  const float* Wv = (const float*)d_in[7];
  const float* bv = (const float*)d_in[8];
  const float* Wo = (const float*)d_in[9];
  const float* bo = (const float*)d_in[10];

  char* ws = (char*)d_ws;
  unsigned short* qbf = (unsigned short*)ws;  ws += (size_t)8192 * 1024 * 2;
  unsigned short* kbf = (unsigned short*)ws;  ws += (size_t)8192 * 512 * 2;
  unsigned short* vbf = (unsigned short*)ws;  ws += (size_t)8192 * 512 * 2;
  unsigned short* Wqt = (unsigned short*)ws;  ws += (size_t)1024 * 1024 * 2;
  unsigned short* Wkt = (unsigned short*)ws;  ws += (size_t)1024 * 512 * 2;
  unsigned short* Wvt = (unsigned short*)ws;  ws += (size_t)1024 * 512 * 2;
  unsigned short* Wot = (unsigned short*)ws;  ws += (size_t)1024 * 1024 * 2;
  unsigned short* Qp  = (unsigned short*)ws;  ws += (size_t)8192 * 1024 * 2;
  unsigned short* Kp  = (unsigned short*)ws;  ws += (size_t)8192 * 1024 * 2;
  unsigned short* Vtp = (unsigned short*)ws;  ws += (size_t)8192 * 1024 * 2;
  unsigned short* Ctx = (unsigned short*)ws;  ws += (size_t)8192 * 1024 * 2;
  float* maskK = (float*)ws;                  ws += (size_t)8192 * 4;
  float* maskV = (float*)ws;                  ws += (size_t)8192 * 4;

  cvtq_kernel<<<8192, 256, 0, stream>>>(query, qbf);
  maskcvt_kernel<<<2048, 256, 0, stream>>>(key, kbf, maskK);
  maskcvt_kernel<<<2048, 256, 0, stream>>>(value, vbf, maskV);
  // fold log2(e)/sqrt(64) into Wq/bq so flash works in exp2 domain
  const float QS = 0.125f * 1.44269504f;
  wtt_kernel<<<dim3(32, 32), dim3(32, 8), 0, stream>>>(Wq, Wqt, 1024, QS);
  wtt_kernel<<<dim3(32, 16), dim3(32, 8), 0, stream>>>(Wk, Wkt, 512, 1.0f);
  wtt_kernel<<<dim3(32, 16), dim3(32, 8), 0, stream>>>(Wv, Wvt, 512, 1.0f);
  wtt_kernel<<<dim3(32, 32), dim3(32, 8), 0, stream>>>(Wo, Wot, 1024, 1.0f);

  gemm_bt_kernel<0, 0, 0><<<dim3(8, 64), 256, 0, stream>>>(qbf, Wqt, bq, nullptr, Qp, 8192, 1024, 1024, QS);
  gemm_bt_kernel<1, 0, 0><<<dim3(8, 64), 256, 0, stream>>>(kbf, Wkt, bk, maskK, Kp, 8192, 1024, 512, 1.0f);
  gemm_bt_kernel<1, 1, 0><<<dim3(8, 64), 256, 0, stream>>>(vbf, Wvt, bv, maskV, Vtp, 8192, 1024, 512, 1.0f);

  flash_kernel<<<dim3(16, 64), 256, 0, stream>>>(Qp, Kp, Vtp, Ctx);

  gemm_bt_kernel<0, 0, 1><<<dim3(8, 64), 256, 0, stream>>>(Ctx, Wot, bo, nullptr, d_out, 8192, 1024, 1024, 1.0f);
}

// Round 9
// 256.800 us; speedup vs baseline: 1.5036x; 1.1217x over previous
//
#include <hip/hip_runtime.h>
#include <hip/hip_bf16.h>

typedef __attribute__((ext_vector_type(8))) short bf16x8;
typedef __attribute__((ext_vector_type(4))) float floatx4;
typedef __attribute__((ext_vector_type(16))) float floatx16;
typedef __attribute__((ext_vector_type(4))) unsigned short u16x4;
typedef __attribute__((ext_vector_type(4))) int intx4;

#define MFMA16(a, b, c) __builtin_amdgcn_mfma_f32_16x16x32_bf16(a, b, c, 0, 0, 0)
#define MFMA32(a, b, c) __builtin_amdgcn_mfma_f32_32x32x16_bf16(a, b, c, 0, 0, 0)

__device__ __forceinline__ unsigned short f2bf(float f) {
  unsigned int u = __float_as_uint(f);
  u += 0x7fffu + ((u >> 16) & 1u);   // round-to-nearest-even
  return (unsigned short)(u >> 16);
}

// compiler-chosen packed f32->bf16x2 (low = first arg)
__device__ __forceinline__ unsigned int pkbf2(float lo, float hi) {
  __hip_bfloat162 h = __float22bfloat162_rn(float2{lo, hi});
  unsigned int r;
  __builtin_memcpy(&r, &h, 4);
  return r;
}

__device__ __forceinline__ void gll16(const void* g, void* l) {
  __builtin_amdgcn_global_load_lds(
      (const __attribute__((address_space(1))) void*)g,
      (__attribute__((address_space(3))) void*)l, 16, 0, 0);
}

// ---------- f32 -> bf16 conversion (query), vectorized ----------
__global__ __launch_bounds__(256) void cvtq_kernel(const float* __restrict__ src,
                                                   unsigned short* __restrict__ dst) {
  int i = blockIdx.x * 256 + threadIdx.x;
  floatx4 v = ((const floatx4*)src)[i];
  u16x4 o;
  o[0] = f2bf(v[0]); o[1] = f2bf(v[1]); o[2] = f2bf(v[2]); o[3] = f2bf(v[3]);
  ((u16x4*)dst)[i] = o;
}

// ---------- key/value: convert + row-sum zero mask (rows of 512 f32) ----------
__global__ __launch_bounds__(256) void maskcvt_kernel(const float* __restrict__ src,
                                                      unsigned short* __restrict__ dst,
                                                      float* __restrict__ mask) {
  const int w = threadIdx.x >> 6, l = threadIdx.x & 63;
  const size_t row = (size_t)blockIdx.x * 4 + w;
  const float* s = src + row * 512;
  float v[8]; float sum = 0.f;
#pragma unroll
  for (int i = 0; i < 8; ++i) { v[i] = s[l + i * 64]; sum += v[i]; }
#pragma unroll
  for (int d = 1; d < 64; d <<= 1) sum += __shfl_xor(sum, d, 64);
  if (l == 0) mask[row] = (sum == 0.0f) ? 0.f : 1.f;
  unsigned short* dr = dst + row * 512;
#pragma unroll
  for (int i = 0; i < 8; ++i) dr[l + i * 64] = f2bf(v[i]);
}

// ---------- weight transpose + convert: W[K][1024] f32 -> Wt[1024][K] bf16 ----------
__global__ __launch_bounds__(256) void wtt_kernel(const float* __restrict__ W,
                                                  unsigned short* __restrict__ Wt,
                                                  int K, float scale) {
  __shared__ float tile[32][33];
  const int tx = threadIdx.x, ty = threadIdx.y;
  const int n_ = blockIdx.x * 32 + tx;
  const int k0 = blockIdx.y * 32;
#pragma unroll
  for (int i = ty; i < 32; i += 8) tile[i][tx] = W[(size_t)(k0 + i) * 1024 + n_];
  __syncthreads();
  const int k_ = k0 + tx;
#pragma unroll
  for (int i = ty; i < 32; i += 8)
    Wt[(size_t)(blockIdx.x * 32 + i) * K + k_] = f2bf(tile[tx][i] * scale);
}

// ---------- GEMM: C[M][N] = A[M][K](bf16) @ Wt[N][K]^T(bf16) + bias, 128x128 tile ----------
// VT path stores V^T with kv-slot bits 2<->3 swapped so flash's PV fragment is
// one contiguous b128 (slot 8hi+p holds kv=(p&3)+8*(p>>2)+4hi within each 16).
template <int MASKF, int VT, int OF32>
__global__ __launch_bounds__(256) void gemm_bt_kernel(
    const unsigned short* __restrict__ A, const unsigned short* __restrict__ Bt,
    const float* __restrict__ bias, const float* __restrict__ mask,
    void* __restrict__ outp, int M, int N, int K, float bscale) {
  __shared__ __align__(16) unsigned short As[2][128 * 32];
  __shared__ __align__(16) unsigned short Bs[2][128 * 32];
  const int t = threadIdx.x;
  const int w = t >> 6, l = t & 63, g = l >> 4, lm = l & 15;
  const int m0 = blockIdx.y * 128, n0 = blockIdx.x * 128;
  const int wm = w >> 1, wn = w & 1;
  floatx4 acc[4][4] = {};

  const int NK = K >> 5;
  auto stage = [&](int kt, int buf) {
#pragma unroll
    for (int issue = 0; issue < 2; ++issue) {
      const int tt = issue * 256 + t;
      gll16(A + (size_t)(m0 + (tt >> 2)) * K + kt * 32 + (tt & 3) * 8,
            (void*)((char*)&As[buf][0] + issue * 4096 + w * 1024));
      gll16(Bt + (size_t)(n0 + (tt >> 2)) * K + kt * 32 + (tt & 3) * 8,
            (void*)((char*)&Bs[buf][0] + issue * 4096 + w * 1024));
    }
  };

  stage(0, 0);
  int cur = 0;
  for (int kt = 0; kt < NK; ++kt) {
    __syncthreads();
    if (kt + 1 < NK) stage(kt + 1, cur ^ 1);
    const unsigned short* Ab = &As[cur][0];
    const unsigned short* Bb = &Bs[cur][0];
    bf16x8 af[4], bfr[4];
#pragma unroll
    for (int mr = 0; mr < 4; ++mr)
      af[mr] = *(const bf16x8*)(Ab + (wm * 64 + mr * 16 + lm) * 32 + g * 8);
#pragma unroll
    for (int nf = 0; nf < 4; ++nf)
      bfr[nf] = *(const bf16x8*)(Bb + (wn * 64 + nf * 16 + lm) * 32 + g * 8);
#pragma unroll
    for (int mr = 0; mr < 4; ++mr)
#pragma unroll
      for (int nf = 0; nf < 4; ++nf)
        acc[mr][nf] = MFMA16(af[mr], bfr[nf], acc[mr][nf]);
    cur ^= 1;
  }

#pragma unroll
  for (int nf = 0; nf < 4; ++nf) {
    const int n = n0 + wn * 64 + nf * 16 + lm;
    const float bv = bias[n] * bscale;
#pragma unroll
    for (int mr = 0; mr < 4; ++mr) {
      const int mb = m0 + wm * 64 + mr * 16 + g * 4;
      if (VT) {
        u16x4 pk;
#pragma unroll
        for (int j = 0; j < 4; ++j) {
          float v = acc[mr][nf][j] + bv;
          if (MASKF) v *= mask[mb + j];
          pk[j] = f2bf(v);
        }
        const int bb = mb >> 11;
        const int s = mb & 2047;                      // kv, %4 == 0
        const int sp = (s & ~12) | ((s & 8) >> 1) | ((s & 4) << 1);  // bit2<->bit3
        *(u16x4*)((unsigned short*)outp + ((size_t)bb * 1024 + n) * 2048 + sp) = pk;
      } else {
#pragma unroll
        for (int j = 0; j < 4; ++j) {
          float v = acc[mr][nf][j] + bv;
          if (MASKF) v *= mask[mb + j];
          if (OF32) ((float*)outp)[(size_t)(mb + j) * N + n] = v;
          else ((unsigned short*)outp)[(size_t)(mb + j) * N + n] = f2bf(v);
        }
      }
    }
  }
}

// ---------- flash attention, swapped-QK^T 32x32, P in-register ----------
// Round-6/8-verified structure. New: single-b128 V fragments (kv-permuted Vt),
// MFMA ones-row sum (replaces 32 adds + shfl), native v_exp_f32, XOR addressing.
__global__ __launch_bounds__(256) void flash_kernel(
    const unsigned short* __restrict__ Qp, const unsigned short* __restrict__ Kp,
    const unsigned short* __restrict__ Vt, unsigned short* __restrict__ Ctx) {
  __shared__ __align__(16) unsigned short Ks[2][64 * 64];
  __shared__ __align__(16) unsigned short Vs[2][64 * 64];
  const int t = threadIdx.x, w = t >> 6, l = t & 63, hi = l >> 5, ln = l & 31;

  // T1: bijective XCD swizzle (nwg=1024, %8==0): each XCD owns 8 contiguous bh
  const int orig = blockIdx.y * 16 + blockIdx.x;
  const int lin = (orig & 7) * 128 + (orig >> 3);
  const int bh = lin >> 4, qt = lin & 15;
  const int b = bh >> 4, h = bh & 15;
  const int q0 = qt * 128 + w * 32;
  const size_t qg = (size_t)b * 2048 + q0;

  // Q fragments (B-operand): lane ln = q, k = kc*16 + hi*8 + j
  bf16x8 qf[4];
#pragma unroll
  for (int kc = 0; kc < 4; ++kc)
    qf[kc] = *(const bf16x8*)(Qp + (qg + ln) * 1024 + h * 64 + kc * 16 + hi * 8);

  bf16x8 onesv;
#pragma unroll
  for (int i = 0; i < 8; ++i) onesv[i] = (short)0x3F80;  // bf16 1.0

  floatx16 oacc[2] = {};
  floatx16 smacc = {};
  float mx = -3.0e38f;

  // chunk XOR base: (kc*2+hi)^(ln&7) == (kc*2) ^ (hi^(ln&7))  [bit0 disjoint]
  const unsigned swz2 = (unsigned)(((ln & 7) ^ hi) << 4);

  // XOR-swizzled staging: LDS slot cs of row holds global chunk cs^(row&7)
  auto stage = [&](int tile, int buf) {
#pragma unroll
    for (int issue = 0; issue < 2; ++issue) {
      const int tt = issue * 256 + t;
      const int row = tt >> 3;
      const int c = (tt & 7) ^ (row & 7);
      gll16(Kp + ((size_t)b * 2048 + tile * 64 + row) * 1024 + h * 64 + c * 8,
            (void*)((char*)&Ks[buf][0] + issue * 4096 + w * 1024));
      gll16(Vt + ((size_t)b * 1024 + h * 64 + row) * 2048 + tile * 64 + c * 8,
            (void*)((char*)&Vs[buf][0] + issue * 4096 + w * 1024));
    }
  };

  stage(0, 0);
  int cur = 0;
  for (int tile = 0; tile < 32; ++tile) {
    __syncthreads();
    if (tile + 1 < 32) stage(tile + 1, cur ^ 1);

    const char* Kb = (const char*)&Ks[cur][0] + (unsigned)(ln * 128) + swz2;
    const char* Vb = (const char*)&Vs[cur][0] + (unsigned)(ln * 128) + swz2;

    // S^T[kv][q], two 32-kv chunks, accumulate over 4 k-chunks of 16
    floatx16 sacc[2] = {};
#pragma unroll
    for (int c = 0; c < 2; ++c) {
#pragma unroll
      for (int kc = 0; kc < 4; ++kc) {
        bf16x8 kf = *(const bf16x8*)((uintptr_t)(Kb + c * 4096) ^ (unsigned)(kc * 32));
        sacc[c] = MFMA32(kf, qf[kc], sacc[c]);
      }
    }

    // online softmax (Q pre-scaled by log2e/sqrt(dk)), T13 defer-max (thr=8)
    float pm = sacc[0][0];
#pragma unroll
    for (int r = 1; r < 16; ++r) pm = fmaxf(pm, sacc[0][r]);
#pragma unroll
    for (int r = 0; r < 16; ++r) pm = fmaxf(pm, sacc[1][r]);
    pm = fmaxf(pm, __shfl_xor(pm, 32, 64));
    if (!__all(pm - mx <= 8.f)) {
      const float mnew = fmaxf(mx, pm);
      const float corr = __builtin_amdgcn_exp2f(mx - mnew);
      mx = mnew;
#pragma unroll
      for (int r = 0; r < 16; ++r) smacc[r] *= corr;
#pragma unroll
      for (int dc = 0; dc < 2; ++dc)
#pragma unroll
        for (int r = 0; r < 16; ++r) oacc[dc][r] *= corr;
    }
#pragma unroll
    for (int c = 0; c < 2; ++c)
#pragma unroll
      for (int r = 0; r < 16; ++r)
        sacc[c][r] = __builtin_amdgcn_exp2f(sacc[c][r] - mx);

    // PV: P packed in natural register order; V fragment = ONE b128 (kv-permuted
    // Vt). k-slot j means kv = 32c+16h2+(j&3)+8*(j>>2)+4hi on BOTH operands.
    // Row-sum via MFMA(A=ones): contracts all 16 k-slots (both lane halves).
#pragma unroll
    for (int c = 0; c < 2; ++c)
#pragma unroll
      for (int h2 = 0; h2 < 2; ++h2) {
        intx4 wd;
#pragma unroll
        for (int wj = 0; wj < 4; ++wj)
          wd[wj] = (int)pkbf2(sacc[c][h2 * 8 + 2 * wj], sacc[c][h2 * 8 + 2 * wj + 1]);
        const bf16x8 pf = __builtin_bit_cast(bf16x8, wd);
        smacc = MFMA32(onesv, pf, smacc);
#pragma unroll
        for (int dc = 0; dc < 2; ++dc) {
          bf16x8 vf = *(const bf16x8*)((uintptr_t)(Vb + dc * 4096) ^ (unsigned)(c * 64 + h2 * 32));
          oacc[dc] = MFMA32(vf, pf, oacc[dc]);
        }
      }
    cur ^= 1;
  }

  // epilogue: lane holds O^T[d = dc*32+crow(r,hi)][q = ln]; all smacc rows equal.
  // Transpose via per-wave LDS (reuse Ks after barrier), then coalesced store.
  __syncthreads();
  const float inv = 1.f / smacc[0];
  unsigned short* lds_o = &Ks[0][0] + w * 2048;  // 4KB per wave: O[q=32][d=64]
#pragma unroll
  for (int dc = 0; dc < 2; ++dc)
#pragma unroll
    for (int r = 0; r < 16; r += 2) {
      const int d = dc * 32 + (r & 3) + 8 * (r >> 2) + 4 * hi;  // even; d+1 next
      const unsigned int pk = pkbf2(oacc[dc][r] * inv, oacc[dc][r + 1] * inv);
      *(unsigned int*)(&lds_o[ln * 64 + (((d >> 3) ^ (ln & 7)) * 8) + (d & 7)]) = pk;
    }
  __builtin_amdgcn_s_waitcnt(0);  // lgkmcnt(0): same-wave LDS RAW
#pragma unroll
  for (int i = 0; i < 4; ++i) {
    const int q = i * 8 + (l >> 3);
    const int cd = l & 7;
    bf16x8 vv = *(const bf16x8*)(&lds_o[q * 64 + ((cd ^ (q & 7)) * 8)]);
    *(bf16x8*)(&Ctx[(qg + q) * 1024 + h * 64 + cd * 8]) = vv;
  }
}

extern "C" void kernel_launch(void* const* d_in, const int* in_sizes, int n_in,
                              void* d_out, int out_size, void* d_ws, size_t ws_size,
                              hipStream_t stream) {
  const float* query = (const float*)d_in[0];
  const float* key   = (const float*)d_in[1];
  const float* value = (const float*)d_in[2];
  const float* Wq = (const float*)d_in[3];
  const float* bq = (const float*)d_in[4];
  const float* Wk = (const float*)d_in[5];
  const float* bk = (const float*)d_in[6];
  const float* Wv = (const float*)d_in[7];
  const float* bv = (const float*)d_in[8];
  const float* Wo = (const float*)d_in[9];
  const float* bo = (const float*)d_in[10];

  char* ws = (char*)d_ws;
  unsigned short* qbf = (unsigned short*)ws;  ws += (size_t)8192 * 1024 * 2;
  unsigned short* kbf = (unsigned short*)ws;  ws += (size_t)8192 * 512 * 2;
  unsigned short* vbf = (unsigned short*)ws;  ws += (size_t)8192 * 512 * 2;
  unsigned short* Wqt = (unsigned short*)ws;  ws += (size_t)1024 * 1024 * 2;
  unsigned short* Wkt = (unsigned short*)ws;  ws += (size_t)1024 * 512 * 2;
  unsigned short* Wvt = (unsigned short*)ws;  ws += (size_t)1024 * 512 * 2;
  unsigned short* Wot = (unsigned short*)ws;  ws += (size_t)1024 * 1024 * 2;
  unsigned short* Qp  = (unsigned short*)ws;  ws += (size_t)8192 * 1024 * 2;
  unsigned short* Kp  = (unsigned short*)ws;  ws += (size_t)8192 * 1024 * 2;
  unsigned short* Vtp = (unsigned short*)ws;  ws += (size_t)8192 * 1024 * 2;
  unsigned short* Ctx = (unsigned short*)ws;  ws += (size_t)8192 * 1024 * 2;
  float* maskK = (float*)ws;                  ws += (size_t)8192 * 4;
  float* maskV = (float*)ws;                  ws += (size_t)8192 * 4;

  cvtq_kernel<<<8192, 256, 0, stream>>>(query, qbf);
  maskcvt_kernel<<<2048, 256, 0, stream>>>(key, kbf, maskK);
  maskcvt_kernel<<<2048, 256, 0, stream>>>(value, vbf, maskV);
  // fold log2(e)/sqrt(64) into Wq/bq so flash works in exp2 domain
  const float QS = 0.125f * 1.44269504f;
  wtt_kernel<<<dim3(32, 32), dim3(32, 8), 0, stream>>>(Wq, Wqt, 1024, QS);
  wtt_kernel<<<dim3(32, 16), dim3(32, 8), 0, stream>>>(Wk, Wkt, 512, 1.0f);
  wtt_kernel<<<dim3(32, 16), dim3(32, 8), 0, stream>>>(Wv, Wvt, 512, 1.0f);
  wtt_kernel<<<dim3(32, 32), dim3(32, 8), 0, stream>>>(Wo, Wot, 1024, 1.0f);

  gemm_bt_kernel<0, 0, 0><<<dim3(8, 64), 256, 0, stream>>>(qbf, Wqt, bq, nullptr, Qp, 8192, 1024, 1024, QS);
  gemm_bt_kernel<1, 0, 0><<<dim3(8, 64), 256, 0, stream>>>(kbf, Wkt, bk, maskK, Kp, 8192, 1024, 512, 1.0f);
  gemm_bt_kernel<1, 1, 0><<<dim3(8, 64), 256, 0, stream>>>(vbf, Wvt, bv, maskV, Vtp, 8192, 1024, 512, 1.0f);

  flash_kernel<<<dim3(16, 64), 256, 0, stream>>>(Qp, Kp, Vtp, Ctx);

  gemm_bt_kernel<0, 0, 1><<<dim3(8, 64), 256, 0, stream>>>(Ctx, Wot, bo, nullptr, d_out, 8192, 1024, 1024, 1.0f);
}

// Round 10
// 238.447 us; speedup vs baseline: 1.6194x; 1.0770x over previous
//
#include <hip/hip_runtime.h>
#include <hip/hip_bf16.h>

typedef __attribute__((ext_vector_type(8))) short bf16x8;
typedef __attribute__((ext_vector_type(4))) float floatx4;
typedef __attribute__((ext_vector_type(16))) float floatx16;
typedef __attribute__((ext_vector_type(4))) unsigned short u16x4;
typedef __attribute__((ext_vector_type(4))) int intx4;

#define MFMA16(a, b, c) __builtin_amdgcn_mfma_f32_16x16x32_bf16(a, b, c, 0, 0, 0)
#define MFMA32(a, b, c) __builtin_amdgcn_mfma_f32_32x32x16_bf16(a, b, c, 0, 0, 0)

__device__ __forceinline__ unsigned short f2bf(float f) {
  unsigned int u = __float_as_uint(f);
  u += 0x7fffu + ((u >> 16) & 1u);   // round-to-nearest-even
  return (unsigned short)(u >> 16);
}

// compiler-chosen packed f32->bf16x2 (low = first arg)
__device__ __forceinline__ unsigned int pkbf2(float lo, float hi) {
  __hip_bfloat162 h = __float22bfloat162_rn(float2{lo, hi});
  unsigned int r;
  __builtin_memcpy(&r, &h, 4);
  return r;
}

__device__ __forceinline__ void gll16(const void* g, void* l) {
  __builtin_amdgcn_global_load_lds(
      (const __attribute__((address_space(1))) void*)g,
      (__attribute__((address_space(3))) void*)l, 16, 0, 0);
}

// ---------- f32 -> bf16 conversion (query), vectorized ----------
__global__ __launch_bounds__(256) void cvtq_kernel(const float* __restrict__ src,
                                                   unsigned short* __restrict__ dst) {
  int i = blockIdx.x * 256 + threadIdx.x;
  floatx4 v = ((const floatx4*)src)[i];
  u16x4 o;
  o[0] = f2bf(v[0]); o[1] = f2bf(v[1]); o[2] = f2bf(v[2]); o[3] = f2bf(v[3]);
  ((u16x4*)dst)[i] = o;
}

// ---------- key/value: convert + row-sum zero mask (rows of 512 f32) ----------
__global__ __launch_bounds__(256) void maskcvt_kernel(const float* __restrict__ src,
                                                      unsigned short* __restrict__ dst,
                                                      float* __restrict__ mask) {
  const int w = threadIdx.x >> 6, l = threadIdx.x & 63;
  const size_t row = (size_t)blockIdx.x * 4 + w;
  const float* s = src + row * 512;
  float v[8]; float sum = 0.f;
#pragma unroll
  for (int i = 0; i < 8; ++i) { v[i] = s[l + i * 64]; sum += v[i]; }
#pragma unroll
  for (int d = 1; d < 64; d <<= 1) sum += __shfl_xor(sum, d, 64);
  if (l == 0) mask[row] = (sum == 0.0f) ? 0.f : 1.f;
  unsigned short* dr = dst + row * 512;
#pragma unroll
  for (int i = 0; i < 8; ++i) dr[l + i * 64] = f2bf(v[i]);
}

// ---------- weight transpose + convert: W[K][1024] f32 -> Wt[1024][K] bf16 ----------
__global__ __launch_bounds__(256) void wtt_kernel(const float* __restrict__ W,
                                                  unsigned short* __restrict__ Wt,
                                                  int K, float scale) {
  __shared__ float tile[32][33];
  const int tx = threadIdx.x, ty = threadIdx.y;
  const int n_ = blockIdx.x * 32 + tx;
  const int k0 = blockIdx.y * 32;
#pragma unroll
  for (int i = ty; i < 32; i += 8) tile[i][tx] = W[(size_t)(k0 + i) * 1024 + n_];
  __syncthreads();
  const int k_ = k0 + tx;
#pragma unroll
  for (int i = ty; i < 32; i += 8)
    Wt[(size_t)(blockIdx.x * 32 + i) * K + k_] = f2bf(tile[tx][i] * scale);
}

// ---------- GEMM: C[M][N] = A[M][K](bf16) @ Wt[N][K]^T(bf16) + bias, 128x128 tile ----------
// VT path stores V^T with kv-slot bits 2<->3 swapped so flash's PV fragment is
// one contiguous b128 (slot 8hi+p holds kv=(p&3)+8*(p>>2)+4hi within each 16).
template <int MASKF, int VT, int OF32>
__global__ __launch_bounds__(256) void gemm_bt_kernel(
    const unsigned short* __restrict__ A, const unsigned short* __restrict__ Bt,
    const float* __restrict__ bias, const float* __restrict__ mask,
    void* __restrict__ outp, int M, int N, int K, float bscale) {
  __shared__ __align__(16) unsigned short As[2][128 * 32];
  __shared__ __align__(16) unsigned short Bs[2][128 * 32];
  const int t = threadIdx.x;
  const int w = t >> 6, l = t & 63, g = l >> 4, lm = l & 15;
  const int m0 = blockIdx.y * 128, n0 = blockIdx.x * 128;
  const int wm = w >> 1, wn = w & 1;
  floatx4 acc[4][4] = {};

  const int NK = K >> 5;
  auto stage = [&](int kt, int buf) {
#pragma unroll
    for (int issue = 0; issue < 2; ++issue) {
      const int tt = issue * 256 + t;
      gll16(A + (size_t)(m0 + (tt >> 2)) * K + kt * 32 + (tt & 3) * 8,
            (void*)((char*)&As[buf][0] + issue * 4096 + w * 1024));
      gll16(Bt + (size_t)(n0 + (tt >> 2)) * K + kt * 32 + (tt & 3) * 8,
            (void*)((char*)&Bs[buf][0] + issue * 4096 + w * 1024));
    }
  };

  stage(0, 0);
  int cur = 0;
  for (int kt = 0; kt < NK; ++kt) {
    __syncthreads();
    if (kt + 1 < NK) stage(kt + 1, cur ^ 1);
    const unsigned short* Ab = &As[cur][0];
    const unsigned short* Bb = &Bs[cur][0];
    bf16x8 af[4], bfr[4];
#pragma unroll
    for (int mr = 0; mr < 4; ++mr)
      af[mr] = *(const bf16x8*)(Ab + (wm * 64 + mr * 16 + lm) * 32 + g * 8);
#pragma unroll
    for (int nf = 0; nf < 4; ++nf)
      bfr[nf] = *(const bf16x8*)(Bb + (wn * 64 + nf * 16 + lm) * 32 + g * 8);
#pragma unroll
    for (int mr = 0; mr < 4; ++mr)
#pragma unroll
      for (int nf = 0; nf < 4; ++nf)
        acc[mr][nf] = MFMA16(af[mr], bfr[nf], acc[mr][nf]);
    cur ^= 1;
  }

#pragma unroll
  for (int nf = 0; nf < 4; ++nf) {
    const int n = n0 + wn * 64 + nf * 16 + lm;
    const float bv = bias[n] * bscale;
#pragma unroll
    for (int mr = 0; mr < 4; ++mr) {
      const int mb = m0 + wm * 64 + mr * 16 + g * 4;
      if (VT) {
        u16x4 pk;
#pragma unroll
        for (int j = 0; j < 4; ++j) {
          float v = acc[mr][nf][j] + bv;
          if (MASKF) v *= mask[mb + j];
          pk[j] = f2bf(v);
        }
        const int bb = mb >> 11;
        const int s = mb & 2047;                      // kv, %4 == 0
        const int sp = (s & ~12) | ((s & 8) >> 1) | ((s & 4) << 1);  // bit2<->bit3
        *(u16x4*)((unsigned short*)outp + ((size_t)bb * 1024 + n) * 2048 + sp) = pk;
      } else {
#pragma unroll
        for (int j = 0; j < 4; ++j) {
          float v = acc[mr][nf][j] + bv;
          if (MASKF) v *= mask[mb + j];
          if (OF32) ((float*)outp)[(size_t)(mb + j) * N + n] = v;
          else ((unsigned short*)outp)[(size_t)(mb + j) * N + n] = f2bf(v);
        }
      }
    }
  }
}

// ---------- flash attention, swapped-QK^T 32x32, QBLK=64 per wave ----------
// Block = (b,h) x 256 q rows; 4 waves x 64 q (2 sets of 32). KVBLK=64.
// Verified structure (rounds 6/9). New: 2 q-sets/wave amortize staging,
// barriers, and V-fragment reads; full-row chunk XOR (row&7 ^ (row>>3)&3)
// kills the residual 4-way bank conflict; 8-wide fmax tree.
__global__ __launch_bounds__(256, 2) void flash_kernel(
    const unsigned short* __restrict__ Qp, const unsigned short* __restrict__ Kp,
    const unsigned short* __restrict__ Vt, unsigned short* __restrict__ Ctx) {
  __shared__ __align__(16) unsigned short Ks[2][64 * 64];
  __shared__ __align__(16) unsigned short Vs[2][64 * 64];
  const int t = threadIdx.x, w = t >> 6, l = t & 63, hi = l >> 5, ln = l & 31;

  // T1: bijective XCD swizzle (nwg=512, %8==0): each XCD owns 8 contiguous bh
  const int orig = blockIdx.y * 8 + blockIdx.x;
  const int lin = (orig & 7) * 64 + (orig >> 3);
  const int bh = lin >> 3, qt = lin & 7;
  const int b = bh >> 4, h = bh & 15;
  const int q0 = qt * 256 + w * 64;
  const size_t qg = (size_t)b * 2048 + q0;

  // Q fragments (B-operand): lane ln = q (set s at +32s), k = kc*16 + hi*8 + j
  bf16x8 qf[2][4];
#pragma unroll
  for (int s = 0; s < 2; ++s)
#pragma unroll
    for (int kc = 0; kc < 4; ++kc)
      qf[s][kc] = *(const bf16x8*)(Qp + (qg + s * 32 + ln) * 1024 + h * 64 + kc * 16 + hi * 8);

  bf16x8 onesv;
#pragma unroll
  for (int i = 0; i < 8; ++i) onesv[i] = (short)0x3F80;  // bf16 1.0

  floatx16 oacc[2][2] = {};
  floatx16 smacc[2] = {};
  float mx[2] = {-3.0e38f, -3.0e38f};

  // chunk XOR: full-row swizzle (row&7) ^ ((row>>3)&3); both lane-constant
  // for fragment reads (row = 32c+ln or 32dc+ln -> c/dc drop out mod 8 and mod 4)
  const unsigned swz2 = (unsigned)((((ln & 7) ^ ((ln >> 3) & 3)) ^ hi) << 4);

  // staging: LDS slot cs of row holds global chunk cs ^ (row&7) ^ ((row>>3)&3)
  auto stage = [&](int tile, int buf) {
#pragma unroll
    for (int issue = 0; issue < 2; ++issue) {
      const int tt = issue * 256 + t;
      const int row = tt >> 3;
      const int c = (tt & 7) ^ (row & 7) ^ ((row >> 3) & 3);
      gll16(Kp + ((size_t)b * 2048 + tile * 64 + row) * 1024 + h * 64 + c * 8,
            (void*)((char*)&Ks[buf][0] + issue * 4096 + w * 1024));
      gll16(Vt + ((size_t)b * 1024 + h * 64 + row) * 2048 + tile * 64 + c * 8,
            (void*)((char*)&Vs[buf][0] + issue * 4096 + w * 1024));
    }
  };

  stage(0, 0);
  int cur = 0;
  for (int tile = 0; tile < 32; ++tile) {
    __syncthreads();
    if (tile + 1 < 32) stage(tile + 1, cur ^ 1);

    const char* Kb = (const char*)&Ks[cur][0] + (unsigned)(ln * 128) + swz2;
    const char* Vb = (const char*)&Vs[cur][0] + (unsigned)(ln * 128) + swz2;

    bf16x8 pf[2][4];
#pragma unroll
    for (int s = 0; s < 2; ++s) {
      // S^T[kv][q-set s], two 32-kv chunks x 4 k-chunks
      floatx16 sacc[2] = {};
#pragma unroll
      for (int c = 0; c < 2; ++c) {
#pragma unroll
        for (int kc = 0; kc < 4; ++kc) {
          bf16x8 kf = *(const bf16x8*)((uintptr_t)(Kb + c * 4096) ^ (unsigned)(kc * 32));
          sacc[c] = MFMA32(kf, qf[s][kc], sacc[c]);
        }
      }

      // max via 8-wide tree (max3-fusable), then cross-half
      float a[8];
#pragma unroll
      for (int i = 0; i < 8; ++i) {
        const int cc = i >> 2, rr = (i & 3) * 4;
        a[i] = fmaxf(fmaxf(sacc[cc][rr], sacc[cc][rr + 1]),
                     fmaxf(sacc[cc][rr + 2], sacc[cc][rr + 3]));
      }
      float pm = fmaxf(fmaxf(fmaxf(a[0], a[1]), fmaxf(a[2], a[3])),
                       fmaxf(fmaxf(a[4], a[5]), fmaxf(a[6], a[7])));
      pm = fmaxf(pm, __shfl_xor(pm, 32, 64));
      // T13 defer-max (thr=8; scores in log2 units)
      if (!__all(pm - mx[s] <= 8.f)) {
        const float mnew = fmaxf(mx[s], pm);
        const float corr = __builtin_amdgcn_exp2f(mx[s] - mnew);
        mx[s] = mnew;
#pragma unroll
        for (int r = 0; r < 16; ++r) smacc[s][r] *= corr;
#pragma unroll
        for (int dc = 0; dc < 2; ++dc)
#pragma unroll
          for (int r = 0; r < 16; ++r) oacc[s][dc][r] *= corr;
      }
#pragma unroll
      for (int c = 0; c < 2; ++c)
#pragma unroll
        for (int r = 0; r < 16; ++r)
          sacc[c][r] = __builtin_amdgcn_exp2f(sacc[c][r] - mx[s]);

      // P -> bf16 B-fragments, natural register order (pairs = consecutive kv)
#pragma unroll
      for (int c = 0; c < 2; ++c)
#pragma unroll
        for (int h2 = 0; h2 < 2; ++h2) {
          intx4 wd;
#pragma unroll
          for (int wj = 0; wj < 4; ++wj)
            wd[wj] = (int)pkbf2(sacc[c][h2 * 8 + 2 * wj], sacc[c][h2 * 8 + 2 * wj + 1]);
          pf[s][c * 2 + h2] = __builtin_bit_cast(bf16x8, wd);
        }
    }

    // PV + row-sum: V fragments shared by both q-sets
#pragma unroll
    for (int c = 0; c < 2; ++c)
#pragma unroll
      for (int h2 = 0; h2 < 2; ++h2) {
        const int kq = c * 2 + h2;
        smacc[0] = MFMA32(onesv, pf[0][kq], smacc[0]);
        smacc[1] = MFMA32(onesv, pf[1][kq], smacc[1]);
#pragma unroll
        for (int dc = 0; dc < 2; ++dc) {
          bf16x8 vf = *(const bf16x8*)((uintptr_t)(Vb + dc * 4096) ^ (unsigned)(c * 64 + h2 * 32));
          oacc[0][dc] = MFMA32(vf, pf[0][kq], oacc[0][dc]);
          oacc[1][dc] = MFMA32(vf, pf[1][kq], oacc[1][dc]);
        }
      }
    cur ^= 1;
  }

  // epilogue: lane holds O^T[d = dc*32+crow(r,hi)][q = ln] per set; inv lane-local.
  // Per-set LDS transpose (per-wave 4KB region of Ks), coalesced b128 stores.
  __syncthreads();
  unsigned short* lds_o = &Ks[0][0] + w * 2048;  // O[q=32][d=64] per set
#pragma unroll
  for (int s = 0; s < 2; ++s) {
    const float inv = 1.f / smacc[s][0];
    if (s) __builtin_amdgcn_s_waitcnt(0);  // set-0 reads done before overwrite
#pragma unroll
    for (int dc = 0; dc < 2; ++dc)
#pragma unroll
      for (int r = 0; r < 16; r += 2) {
        const int d = dc * 32 + (r & 3) + 8 * (r >> 2) + 4 * hi;  // even; d+1 next
        const unsigned int pk = pkbf2(oacc[s][dc][r] * inv, oacc[s][dc][r + 1] * inv);
        *(unsigned int*)(&lds_o[ln * 64 + (((d >> 3) ^ (ln & 7)) * 8) + (d & 7)]) = pk;
      }
    __builtin_amdgcn_s_waitcnt(0);  // lgkmcnt(0): same-wave LDS RAW
#pragma unroll
    for (int i = 0; i < 4; ++i) {
      const int q = i * 8 + (l >> 3);
      const int cd = l & 7;
      bf16x8 vv = *(const bf16x8*)(&lds_o[q * 64 + ((cd ^ (q & 7)) * 8)]);
      *(bf16x8*)(&Ctx[(qg + s * 32 + q) * 1024 + h * 64 + cd * 8]) = vv;
    }
  }
}

extern "C" void kernel_launch(void* const* d_in, const int* in_sizes, int n_in,
                              void* d_out, int out_size, void* d_ws, size_t ws_size,
                              hipStream_t stream) {
  const float* query = (const float*)d_in[0];
  const float* key   = (const float*)d_in[1];
  const float* value = (const float*)d_in[2];
  const float* Wq = (const float*)d_in[3];
  const float* bq = (const float*)d_in[4];
  const float* Wk = (const float*)d_in[5];
  const float* bk = (const float*)d_in[6];
  const float* Wv = (const float*)d_in[7];
  const float* bv = (const float*)d_in[8];
  const float* Wo = (const float*)d_in[9];
  const float* bo = (const float*)d_in[10];

  char* ws = (char*)d_ws;
  unsigned short* qbf = (unsigned short*)ws;  ws += (size_t)8192 * 1024 * 2;
  unsigned short* kbf = (unsigned short*)ws;  ws += (size_t)8192 * 512 * 2;
  unsigned short* vbf = (unsigned short*)ws;  ws += (size_t)8192 * 512 * 2;
  unsigned short* Wqt = (unsigned short*)ws;  ws += (size_t)1024 * 1024 * 2;
  unsigned short* Wkt = (unsigned short*)ws;  ws += (size_t)1024 * 512 * 2;
  unsigned short* Wvt = (unsigned short*)ws;  ws += (size_t)1024 * 512 * 2;
  unsigned short* Wot = (unsigned short*)ws;  ws += (size_t)1024 * 1024 * 2;
  unsigned short* Qp  = (unsigned short*)ws;  ws += (size_t)8192 * 1024 * 2;
  unsigned short* Kp  = (unsigned short*)ws;  ws += (size_t)8192 * 1024 * 2;
  unsigned short* Vtp = (unsigned short*)ws;  ws += (size_t)8192 * 1024 * 2;
  unsigned short* Ctx = (unsigned short*)ws;  ws += (size_t)8192 * 1024 * 2;
  float* maskK = (float*)ws;                  ws += (size_t)8192 * 4;
  float* maskV = (float*)ws;                  ws += (size_t)8192 * 4;

  cvtq_kernel<<<8192, 256, 0, stream>>>(query, qbf);
  maskcvt_kernel<<<2048, 256, 0, stream>>>(key, kbf, maskK);
  maskcvt_kernel<<<2048, 256, 0, stream>>>(value, vbf, maskV);
  // fold log2(e)/sqrt(64) into Wq/bq so flash works in exp2 domain
  const float QS = 0.125f * 1.44269504f;
  wtt_kernel<<<dim3(32, 32), dim3(32, 8), 0, stream>>>(Wq, Wqt, 1024, QS);
  wtt_kernel<<<dim3(32, 16), dim3(32, 8), 0, stream>>>(Wk, Wkt, 512, 1.0f);
  wtt_kernel<<<dim3(32, 16), dim3(32, 8), 0, stream>>>(Wv, Wvt, 512, 1.0f);
  wtt_kernel<<<dim3(32, 32), dim3(32, 8), 0, stream>>>(Wo, Wot, 1024, 1.0f);

  gemm_bt_kernel<0, 0, 0><<<dim3(8, 64), 256, 0, stream>>>(qbf, Wqt, bq, nullptr, Qp, 8192, 1024, 1024, QS);
  gemm_bt_kernel<1, 0, 0><<<dim3(8, 64), 256, 0, stream>>>(kbf, Wkt, bk, maskK, Kp, 8192, 1024, 512, 1.0f);
  gemm_bt_kernel<1, 1, 0><<<dim3(8, 64), 256, 0, stream>>>(vbf, Wvt, bv, maskV, Vtp, 8192, 1024, 512, 1.0f);

  flash_kernel<<<dim3(8, 64), 256, 0, stream>>>(Qp, Kp, Vtp, Ctx);

  gemm_bt_kernel<0, 0, 1><<<dim3(8, 64), 256, 0, stream>>>(Ctx, Wot, bo, nullptr, d_out, 8192, 1024, 1024, 1.0f);
}